// Round 7
// baseline (79.621 us; speedup 1.0000x reference)
//
#include <hip/hip_runtime.h>
#include <math.h>

// Problem dims (fixed by reference)
#define BDIM 2048
#define ODIM 256
#define IDIM 256
#define NZ   8                      // j-splits
#define JBLK (IDIM / NZ)            // 32 j per block
#define NJQ  (JBLK / 4)             // 8 j-quads (float4 of angles)
#define ZBASE ((float)(IDIM / NZ))  // 32.0f; per-z share of the +IDIM base

// out[b,o] = IDIM + C * sum_j 1/(D - 2at*cos(phi0 + x[b,j] + p[o,j]))
//   C = (t^2-1)(1-a^2),  D = 1+(at)^2
//
// R16: ANGLE-LDS formulation. Instead of storing (cos,sin) margins (2 f32
// per row,j -> 16B/jq/row of reads), store ANGLES IN REVOLUTIONS (1 f32):
//   rx = (phi0+x)/2pi, rp = p/2pi;  c = v_cos(v_fract(rx+rp))   [HW takes revs]
//   den = fma(-2at, c, D);  quad-rcp over 4 j as before.
// Effects vs R9/R15 ledger model t = 336/w + LDS_pipe:
//   - LDS reads halve: 6 b128/jq/thread (4 A + 2 P), 393k wave-insts
//   - LDS size 12 KB/block (A 8KB swizzled + P 4KB)
//   - prologue sincos GONE (just fma-scale)
//   - VGPR working set ~55-70 (no 32-reg margin staging)
// => tile 64x32, grid (8,32,8)=2048 blocks, launch_bounds(256,6):
//    6 blocks/CU = 24 waves/CU at NZ=8 (atomics stay 8-writer, 4.2M,
//    proven free by R12). Model: 336/24 + ~8.5 = 22-25us kernel.
// Banks: Ax[row][col ^ (row&3)] -> the 4 broadcast rows/read hit 4
// distinct bank-quads (conflict-free, 2 VALU xor per jq); Po[jq][o]
// o-innermost -> 2-way (free).

__global__ __launch_bounds__(256, 6)
void photonic_fused(const float* __restrict__ X,   // [BDIM][IDIM]
                    const float* __restrict__ P,   // [ODIM][IDIM]
                    float* __restrict__ Out,       // [BDIM][ODIM] (+= semantics)
                    float phi0r, float inv2pi, float m2at,
                    float Dc, float Cnum) {
    __shared__ float4 Ax[64][NJQ];   // 8192 B: angle-quads, col XOR-swizzled by (row&3)
    __shared__ float4 Po[NJQ][32];   // 4096 B: [jq][o], o innermost

    const int tid = threadIdx.x;
    const int tx  = tid & 15;            // o sub-index 0..15
    const int ty  = tid >> 4;            // b sub-index 0..15
    const int o0  = blockIdx.x * 32;
    const int b0  = blockIdx.y * 64;
    const int j0  = blockIdx.z * JBLK;

    // ---- prologue: scale raw phases to revolutions, store angles ----
    {
        const int r  = tid & 63;         // X row 0..63
        const int cb = (tid >> 6) * 2;   // col pair base 0,2,4,6
        #pragma unroll
        for (int i = 0; i < 2; ++i) {
            const int c = cb + i;
            float4 x = *(const float4*)(X + (size_t)(b0 + r) * IDIM + j0 + 4 * c);
            float4 rx;
            rx.x = fmaf(x.x, inv2pi, phi0r);
            rx.y = fmaf(x.y, inv2pi, phi0r);
            rx.z = fmaf(x.z, inv2pi, phi0r);
            rx.w = fmaf(x.w, inv2pi, phi0r);
            Ax[r][c ^ (r & 3)] = rx;
        }
        const int pj = tid >> 5;         // jq 0..7
        const int oo = tid & 31;         // o 0..31
        float4 pv = *(const float4*)(P + (size_t)(o0 + oo) * IDIM + j0 + 4 * pj);
        float4 rp;
        rp.x = pv.x * inv2pi;
        rp.y = pv.y * inv2pi;
        rp.z = pv.z * inv2pi;
        rp.w = pv.w * inv2pi;
        Po[pj][oo] = rp;
    }
    __syncthreads();

    float acc[4][2];
    #pragma unroll
    for (int k = 0; k < 4; ++k) { acc[k][0] = 0.f; acc[k][1] = 0.f; }

    const int tysw = ty & 3;

    #pragma unroll 2
    for (int jq = 0; jq < NJQ; ++jq) {
        const float4 rpA = Po[jq][tx];        // o = tx
        const float4 rpB = Po[jq][tx + 16];   // o = tx+16
        const int    csw = jq ^ tysw;         // swizzled col, k-invariant
        #pragma unroll
        for (int k = 0; k < 4; ++k) {
            const float4 rx = Ax[ty + 16 * k][csw];
            #pragma unroll
            for (int oh = 0; oh < 2; ++oh) {
                const float4 rp = oh ? rpB : rpA;
                float d0, d1, d2, d3;
                {
                    float f, c;
                    f = __builtin_amdgcn_fractf(rx.x + rp.x);
                    c = __builtin_amdgcn_cosf(f);
                    d0 = fmaf(m2at, c, Dc);
                    f = __builtin_amdgcn_fractf(rx.y + rp.y);
                    c = __builtin_amdgcn_cosf(f);
                    d1 = fmaf(m2at, c, Dc);
                    f = __builtin_amdgcn_fractf(rx.z + rp.z);
                    c = __builtin_amdgcn_cosf(f);
                    d2 = fmaf(m2at, c, Dc);
                    f = __builtin_amdgcn_fractf(rx.w + rp.w);
                    c = __builtin_amdgcn_cosf(f);
                    d3 = fmaf(m2at, c, Dc);
                }
                // quad-rcp: sum of 1/d over the 4 j's with one rcp
                const float p01 = d0 * d1, p23 = d2 * d3;
                const float s01 = d0 + d1, s23 = d2 + d3;
                const float n  = fmaf(s01, p23, s23 * p01);
                const float q  = p01 * p23;
                const float rq = __builtin_amdgcn_rcpf(q);
                acc[k][oh] = fmaf(n, rq, acc[k][oh]);
            }
        }
    }

    // ---- atomic epilogue: base folded in as +ZBASE per z-plane ----
    #pragma unroll
    for (int k = 0; k < 4; ++k)
        #pragma unroll
        for (int oh = 0; oh < 2; ++oh) {
            const int b = b0 + ty + 16 * k;
            const int o = o0 + tx + 16 * oh;
            unsafeAtomicAdd(&Out[(size_t)b * ODIM + o], fmaf(Cnum, acc[k][oh], ZBASE));
        }
}

extern "C" void kernel_launch(void* const* d_in, const int* in_sizes, int n_in,
                              void* d_out, int out_size, void* d_ws, size_t ws_size,
                              hipStream_t stream) {
    const float* X = (const float*)d_in[0];   // input_matrix [2048,256] f32
    const float* P = (const float*)d_in[1];   // phase_offset [256,256] f32
    float* Out = (float*)d_out;               // [2048,256] f32

    const double RADIUS = 5e-6, KAPPA = 0.1, N_EFF = 3.48, LAMBDA = 1.55e-6, LOSS_A = 0.99;
    const double TWO_PI = 6.283185307179586476925286766559;
    const double t  = sqrt(1.0 - KAPPA);
    const double a  = LOSS_A;
    const double at = a * t;
    const double phi0 = fmod(TWO_PI * N_EFF * (TWO_PI * RADIUS) / LAMBDA, TWO_PI);
    const double D    = 1.0 + at * at;
    const double Cnum = (t * t - 1.0) * (1.0 - a * a);   // num - den (constant)

    // 8 o-tiles x 32 b-tiles x 8 j-splits = 2048 blocks of 256 thr
    // (12 KB LDS, ~60-70 VGPR -> 6 blocks/CU = 24 waves/CU)
    dim3 grid(ODIM / 32, BDIM / 64, NZ);
    photonic_fused<<<grid, 256, 0, stream>>>(
        X, P, Out,
        (float)(phi0 / TWO_PI), (float)(1.0 / TWO_PI), (float)(-2.0 * at),
        (float)D, (float)Cnum);
}

// Round 8
// 79.534 us; speedup vs baseline: 1.0011x; 1.0011x over previous
//
#include <hip/hip_runtime.h>
#include <math.h>

// Problem dims (fixed by reference)
#define BDIM 2048
#define ODIM 256
#define IDIM 256
#define NZ   8                      // j-splits
#define JBLK (IDIM / NZ)            // 32 j per block
#define NJQ  (JBLK / 4)             // 8 j-quads
#define ZBASE ((float)(IDIM / NZ))  // 32.0f; per-z share of the +IDIM base

typedef float v2f __attribute__((ext_vector_type(2)));

// out[b,o] = IDIM + C * sum_j 1/(D - 2at*cos(phi0 + x[b,j] + p[o,j]))
//   C = (t^2-1)(1-a^2),  D = 1+(at)^2
// cos(x'+p) = cos x' cos p - sin x' sin p =>
//   den = D + mc*pc + ms*ps,  mc=-2at*cos(phi0+x), ms=2at*sin(phi0+x)
//
// R17: HYBRID margin sourcing. Ledger model t = 336/w + 11*(LDS/524k);
// all pure-LDS configs bottom out ~25us (LDS capacity vs VGPR caps vs
// NZ=16 atomic penalty). New lever: P-margins are b-invariant -> compute
// them ONCE in a pre-kernel into workspace (512 KB; R12 proved ws>=16.8MB
// usable) and read them in the hot loop from GLOBAL via L1 (16 KB slice
// per block, 8x wave-level reuse, 256 B contiguous per inst on the TA
// pipe - parallel to the LDS pipe). A-margins stay in LDS (broadcast
// pattern, proven free). Effects: LDS insts 524k->262k (term 11->5.5us),
// LDS size 17.4 KB, VALU unchanged (PMB layout {pc_lo,pc_hi,ps_lo,ps_hi}
// keeps v2f operands load-adjacent, zero repack). Config: 512thr, 64x64
// tile, 2b x 4o (R13's proven shape/caps), launch_bounds(512,6) -> 24
// waves/CU. Atomics 4.2M 8-writer (proven free, R12).
// Pred: 336/24 + 5.5 + pre/launch ~3 => dur ~64-68.

// ---------- pre-kernel: P margins ----------
// PMB[j][op] = {cos P[ol][j], cos P[oh][j], sin P[ol][j], sin P[oh][j]}
//   op in [0,128): ol = (op>>4)*32 + (op&15), oh = ol + 16
__global__ __launch_bounds__(128)
void photonic_pmarg(const float* __restrict__ P, float4* __restrict__ PMB) {
    const int j  = blockIdx.x;          // 0..255
    const int op = threadIdx.x;         // 0..127
    const int ol = ((op >> 4) << 5) + (op & 15);
    const int oh = ol + 16;
    float sl, cl, sh, ch;
    __sincosf(P[(size_t)ol * IDIM + j], &sl, &cl);
    __sincosf(P[(size_t)oh * IDIM + j], &sh, &ch);
    PMB[(size_t)j * 128 + op] = make_float4(cl, ch, sl, sh);
}

// ---------- main hybrid kernel ----------
__global__ __launch_bounds__(512, 6)
void photonic_hyb(const float* __restrict__ X,     // [BDIM][IDIM]
                  const float4* __restrict__ PMB,  // [IDIM][128] margin quads
                  float* __restrict__ Out,         // [BDIM][ODIM] (+= semantics)
                  float phi0, float m2at, float p2at,
                  float Dc, float Cnum) {
    __shared__ float4 As4[64][17];       // 17408 B (slot 16 = pad)

    const int tid = threadIdx.x;
    const int tx  = tid & 15;            // o sub-index 0..15
    const int ty  = (tid >> 4) & 15;     // b sub-index 0..15
    const int hf  = tid >> 8;            // k-half 0/1
    const int o0  = blockIdx.x * 64;
    const int b0  = blockIdx.y * 64;
    const int j0  = blockIdx.z * JBLK;

    // ---- prologue: A-side sincos margins into LDS (one b128 per thread) ----
    {
        const int r  = tid >> 3;         // 0..63
        const int jq = tid & 7;          // 0..7
        float s0, c0, s1, c1, s2, c2, s3, c3;
        float4 x = *(const float4*)(X + (size_t)(b0 + r) * IDIM + j0 + 4 * jq);
        __sincosf(phi0 + x.x, &s0, &c0);
        __sincosf(phi0 + x.y, &s1, &c1);
        __sincosf(phi0 + x.z, &s2, &c2);
        __sincosf(phi0 + x.w, &s3, &c3);
        As4[r][2 * jq]     = make_float4(m2at * c0, m2at * c1, m2at * c2, m2at * c3);
        As4[r][2 * jq + 1] = make_float4(p2at * s0, p2at * s1, p2at * s2, p2at * s3);
    }
    __syncthreads();

    v2f acc[2][2];
    acc[0][0] = acc[0][1] = acc[1][0] = acc[1][1] = (v2f){0.f, 0.f};
    const v2f D2 = {Dc, Dc};

    // P-margin base: column op0 = (o0>>5)*16 + tx, row j0 (p adds +16, j adds +128)
    const float4* PB = PMB + (size_t)j0 * 128 + ((o0 >> 5) << 4) + tx;

    #pragma unroll 2
    for (int jq = 0; jq < NJQ; ++jq) {
        // P operands for this j-quad from L1: 8 x b128 (256 B contiguous/wave)
        float4 g[2][4];                  // [p][j]
        #pragma unroll
        for (int j = 0; j < 4; ++j) {
            g[0][j] = PB[(size_t)(4 * jq + j) * 128];
            g[1][j] = PB[(size_t)(4 * jq + j) * 128 + 16];
        }
        #pragma unroll
        for (int k = 0; k < 2; ++k) {
            const int row = ty + 16 * (2 * hf + k);
            float4 mc4 = As4[row][2 * jq];
            float4 ms4 = As4[row][2 * jq + 1];
            float mcf[4] = {mc4.x, mc4.y, mc4.z, mc4.w};
            float msf[4] = {ms4.x, ms4.y, ms4.z, ms4.w};
            #pragma unroll
            for (int p = 0; p < 2; ++p) {
                v2f d[4];
                #pragma unroll
                for (int j = 0; j < 4; ++j) {
                    v2f pc = {g[p][j].x, g[p][j].y};
                    v2f ps = {g[p][j].z, g[p][j].w};
                    v2f t = __builtin_elementwise_fma((v2f){msf[j], msf[j]}, ps, D2);
                    d[j]  = __builtin_elementwise_fma((v2f){mcf[j], mcf[j]}, pc, t);
                }
                // quad-rcp over the 4 j's, vectorized over the o-pair
                v2f p01 = d[0] * d[1], p23 = d[2] * d[3];
                v2f s01 = d[0] + d[1], s23 = d[2] + d[3];
                v2f n = __builtin_elementwise_fma(s01, p23, s23 * p01);
                v2f qq = p01 * p23;
                v2f r = {__builtin_amdgcn_rcpf(qq.x), __builtin_amdgcn_rcpf(qq.y)};
                acc[k][p] = __builtin_elementwise_fma(n, r, acc[k][p]);
            }
        }
    }

    // ---- atomic epilogue: base folded in as +ZBASE per z-plane ----
    #pragma unroll
    for (int k = 0; k < 2; ++k)
        #pragma unroll
        for (int p = 0; p < 2; ++p) {
            const int b = b0 + ty + 16 * (2 * hf + k);
            const int o = o0 + p * 32 + tx;
            unsafeAtomicAdd(&Out[(size_t)b * ODIM + o],      fmaf(Cnum, acc[k][p].x, ZBASE));
            unsafeAtomicAdd(&Out[(size_t)b * ODIM + o + 16], fmaf(Cnum, acc[k][p].y, ZBASE));
        }
}

// ---------- fallback (R13 exact, self-contained): used only if ws too small ----------
__global__ __launch_bounds__(512, 6)
void photonic_fb(const float* __restrict__ X, const float* __restrict__ P,
                 float* __restrict__ Out,
                 float phi0, float m2at, float p2at, float Dc, float Cnum) {
    __shared__ float4 As4[64][17];
    __shared__ float4 SP4[JBLK][2][16];

    const int tid = threadIdx.x;
    const int tx  = tid & 15;
    const int ty  = (tid >> 4) & 15;
    const int hf  = tid >> 8;
    const int o0  = blockIdx.x * 64;
    const int b0  = blockIdx.y * 64;
    const int j0  = blockIdx.z * JBLK;

    {
        const int r  = tid >> 3;
        const int jq = tid & 7;
        float s0, c0, s1, c1, s2, c2, s3, c3;
        float4 x = *(const float4*)(X + (size_t)(b0 + r) * IDIM + j0 + 4 * jq);
        __sincosf(phi0 + x.x, &s0, &c0);
        __sincosf(phi0 + x.y, &s1, &c1);
        __sincosf(phi0 + x.z, &s2, &c2);
        __sincosf(phi0 + x.w, &s3, &c3);
        As4[r][2 * jq]     = make_float4(m2at * c0, m2at * c1, m2at * c2, m2at * c3);
        As4[r][2 * jq + 1] = make_float4(p2at * s0, p2at * s1, p2at * s2, p2at * s3);

        float4 pv = *(const float4*)(P + (size_t)(o0 + r) * IDIM + j0 + 4 * jq);
        __sincosf(pv.x, &s0, &c0);
        __sincosf(pv.y, &s1, &c1);
        __sincosf(pv.z, &s2, &c2);
        __sincosf(pv.w, &s3, &c3);
        const int pr  = r >> 5;
        const int hi  = (r >> 4) & 1;
        const int tx_ = r & 15;
        float cs[4] = {c0, c1, c2, c3};
        float ss[4] = {s0, s1, s2, s3};
        #pragma unroll
        for (int jj = 0; jj < 4; ++jj) {
            float* cell = (float*)&SP4[4 * (tid & 7) + jj][pr][tx_];
            cell[hi]     = cs[jj];
            cell[2 + hi] = ss[jj];
        }
    }
    __syncthreads();

    v2f acc[2][2];
    acc[0][0] = acc[0][1] = acc[1][0] = acc[1][1] = (v2f){0.f, 0.f};
    const v2f D2 = {Dc, Dc};

    #pragma unroll 2
    for (int jq = 0; jq < NJQ; ++jq) {
        float4 q0[4], q1[4];
        #pragma unroll
        for (int j = 0; j < 4; ++j) {
            q0[j] = SP4[4 * jq + j][0][tx];
            q1[j] = SP4[4 * jq + j][1][tx];
        }
        #pragma unroll
        for (int k = 0; k < 2; ++k) {
            const int row = ty + 16 * (2 * hf + k);
            float4 mc4 = As4[row][2 * jq];
            float4 ms4 = As4[row][2 * jq + 1];
            float mcf[4] = {mc4.x, mc4.y, mc4.z, mc4.w};
            float msf[4] = {ms4.x, ms4.y, ms4.z, ms4.w};
            #pragma unroll
            for (int p = 0; p < 2; ++p) {
                const float4* q = (p == 0) ? q0 : q1;
                v2f d[4];
                #pragma unroll
                for (int j = 0; j < 4; ++j) {
                    v2f pc = {q[j].x, q[j].y};
                    v2f ps = {q[j].z, q[j].w};
                    v2f t = __builtin_elementwise_fma((v2f){msf[j], msf[j]}, ps, D2);
                    d[j]  = __builtin_elementwise_fma((v2f){mcf[j], mcf[j]}, pc, t);
                }
                v2f p01 = d[0] * d[1], p23 = d[2] * d[3];
                v2f s01 = d[0] + d[1], s23 = d[2] + d[3];
                v2f n = __builtin_elementwise_fma(s01, p23, s23 * p01);
                v2f qq = p01 * p23;
                v2f r = {__builtin_amdgcn_rcpf(qq.x), __builtin_amdgcn_rcpf(qq.y)};
                acc[k][p] = __builtin_elementwise_fma(n, r, acc[k][p]);
            }
        }
    }

    #pragma unroll
    for (int k = 0; k < 2; ++k)
        #pragma unroll
        for (int p = 0; p < 2; ++p) {
            const int b = b0 + ty + 16 * (2 * hf + k);
            const int o = o0 + p * 32 + tx;
            unsafeAtomicAdd(&Out[(size_t)b * ODIM + o],      fmaf(Cnum, acc[k][p].x, ZBASE));
            unsafeAtomicAdd(&Out[(size_t)b * ODIM + o + 16], fmaf(Cnum, acc[k][p].y, ZBASE));
        }
}

extern "C" void kernel_launch(void* const* d_in, const int* in_sizes, int n_in,
                              void* d_out, int out_size, void* d_ws, size_t ws_size,
                              hipStream_t stream) {
    const float* X = (const float*)d_in[0];   // input_matrix [2048,256] f32
    const float* P = (const float*)d_in[1];   // phase_offset [256,256] f32
    float* Out = (float*)d_out;               // [2048,256] f32

    const double RADIUS = 5e-6, KAPPA = 0.1, N_EFF = 3.48, LAMBDA = 1.55e-6, LOSS_A = 0.99;
    const double TWO_PI = 6.283185307179586476925286766559;
    const double t  = sqrt(1.0 - KAPPA);
    const double a  = LOSS_A;
    const double at = a * t;
    const double phi0 = fmod(TWO_PI * N_EFF * (TWO_PI * RADIUS) / LAMBDA, TWO_PI);
    const double D    = 1.0 + at * at;
    const double Cnum = (t * t - 1.0) * (1.0 - a * a);   // num - den (constant)

    const size_t pm_need = (size_t)IDIM * 128 * sizeof(float4);  // 512 KB

    dim3 grid(ODIM / 64, BDIM / 64, NZ);    // 1024 blocks of 512 thr
    if (d_ws != nullptr && ws_size >= pm_need) {
        float4* PMB = (float4*)d_ws;
        photonic_pmarg<<<dim3(IDIM), 128, 0, stream>>>(P, PMB);
        photonic_hyb<<<grid, 512, 0, stream>>>(
            X, PMB, Out,
            (float)phi0, (float)(-2.0 * at), (float)(2.0 * at),
            (float)D, (float)Cnum);
    } else {
        photonic_fb<<<grid, 512, 0, stream>>>(
            X, P, Out,
            (float)phi0, (float)(-2.0 * at), (float)(2.0 * at),
            (float)D, (float)Cnum);
    }
}